// Round 7
// baseline (230.449 us; speedup 1.0000x reference)
//
#include <hip/hip_runtime.h>

#define SL  2048
#define BSZ 32
#define DIM 1024
#define NH  16
#define HD  64

typedef __attribute__((ext_vector_type(4))) float f32x4;
typedef __attribute__((ext_vector_type(8))) short s16x8;

static __device__ __forceinline__ short f2bf(float f) {
    union { float f; unsigned u; } v; v.f = f;
    unsigned r = (v.u + 0x7fffu + ((v.u >> 16) & 1u)) >> 16;  // RNE
    return (short)r;
}

// Fused q-projection + u: u[b][h][j] = 0.125 * sum_i (query[b].Wq[h*64+i]) * Wk[h*64+i][j]
// grid 128 = 16 h x 8 bg (4 b each); block 256 = 4 waves (wave = k-quarter in stage 1).
// Wq/Wk h-slices read ONCE per block -> x8 amplification (was x32).
__global__ __launch_bounds__(256) void k_qu(const float* __restrict__ query,
                                            const float* __restrict__ Wq,
                                            const float* __restrict__ Wk,
                                            short* __restrict__ u) {
    int h  = blockIdx.x >> 3;
    int bg = blockIdx.x & 7;
    int b0 = bg * 4;
    int t = threadIdx.x;
    __shared__ float qlds[4][DIM];      // 16 KB
    __shared__ float red[4][64][4];     // [kq][i][bb] 4 KB
    __shared__ float sq[4][HD];         // 1 KB

    // stage 4 query rows
#pragma unroll
    for (int r = 0; r < 4; ++r) {
        int idx = t + r * 256;          // bb = r
        int kk = (idx & 255) * 4;
        *(f32x4*)&qlds[r][kk] = *(const f32x4*)(query + (size_t)(b0 + r) * DIM + kk);
    }
    __syncthreads();
    {   // stage 1: lane=i (0..63), wave=kq; 4 b accumulators
        int i = t & 63, kq = t >> 6;
        const float* wrow = Wq + (size_t)(h * HD + i) * DIM + kq * 256;
        const float* q0 = &qlds[0][kq * 256];
        const float* q1 = &qlds[1][kq * 256];
        const float* q2 = &qlds[2][kq * 256];
        const float* q3 = &qlds[3][kq * 256];
        f32x4 a0 = {0,0,0,0}, a1 = {0,0,0,0}, a2 = {0,0,0,0}, a3 = {0,0,0,0};
#pragma unroll 4
        for (int k = 0; k < 256; k += 4) {
            f32x4 wv = *(const f32x4*)(wrow + k);
            a0 += wv * *(const f32x4*)(q0 + k);
            a1 += wv * *(const f32x4*)(q1 + k);
            a2 += wv * *(const f32x4*)(q2 + k);
            a3 += wv * *(const f32x4*)(q3 + k);
        }
        red[kq][i][0] = a0[0]+a0[1]+a0[2]+a0[3];
        red[kq][i][1] = a1[0]+a1[1]+a1[2]+a1[3];
        red[kq][i][2] = a2[0]+a2[1]+a2[2]+a2[3];
        red[kq][i][3] = a3[0]+a3[1]+a3[2]+a3[3];
    }
    __syncthreads();
    {
        int bb = t & 3, i = t >> 2;
        sq[bb][i] = (red[0][i][bb] + red[1][i][bb] + red[2][i][bb] + red[3][i][bb]) * 0.125f;
    }
    __syncthreads();
    // stage 2: thread owns 4 j cols (f32x4), 4 b accumulators
    f32x4 acc[4];
#pragma unroll
    for (int bb = 0; bb < 4; ++bb) acc[bb] = (f32x4){0,0,0,0};
    const float* wk = Wk + (size_t)(h * HD) * DIM + t * 4;
#pragma unroll 8
    for (int i = 0; i < HD; ++i) {
        f32x4 wv = *(const f32x4*)(wk + (size_t)i * DIM);
        acc[0] += sq[0][i] * wv;
        acc[1] += sq[1][i] * wv;
        acc[2] += sq[2][i] * wv;
        acc[3] += sq[3][i] * wv;
    }
#pragma unroll
    for (int bb = 0; bb < 4; ++bb) {
        ushort4 o;
        o.x = (unsigned short)f2bf(acc[bb][0]);
        o.y = (unsigned short)f2bf(acc[bb][1]);
        o.z = (unsigned short)f2bf(acc[bb][2]);
        o.w = (unsigned short)f2bf(acc[bb][3]);
        *(ushort4*)(u + ((size_t)((b0 + bb) * NH + h)) * DIM + t * 4) = o;
    }
}

// dot[b][s][h] = keys[s,b,:].u[b,h,:]  via LDS-staged keys (contiguous 1KB reads).
// grid 4096 = 128 st x 32 b (b fastest); block 256 = 4 waves, each wave a K-quarter.
__global__ __launch_bounds__(256) void k_dot2(const float* __restrict__ keys,
                                              const short* __restrict__ u,
                                              float* __restrict__ dot,
                                              float2* __restrict__ part) {
    int b  = blockIdx.x & 31;
    int st = blockIdx.x >> 5;          // 0..127
    int s0 = st * 16;
    __shared__ short ulds[NH][DIM + 8];
    __shared__ short klds[16][DIM + 8];
    __shared__ f32x4 redc[4][64];
    int t = threadIdx.x;
    int w = t >> 6, l = t & 63;

    {   // stage u (L2-hot, ~1 MB/b shared across 128 st-blocks)
        const uint4* src = (const uint4*)(u + (size_t)b * NH * DIM);
        for (int idx = t; idx < NH * DIM / 8; idx += 256) {
            int row = idx >> 7;
            int col = (idx & 127) * 8;
            *(uint4*)&ulds[row][col] = src[idx];
        }
    }
    // stage keys -> bf16; each wave 4 rows, lane-k-major: 1KB contiguous per instr
#pragma unroll
    for (int r = 0; r < 4; ++r) {
        int srow = w * 4 + r;
        const float* kr = keys + ((size_t)(s0 + srow) * BSZ + b) * DIM;
#pragma unroll
        for (int kq = 0; kq < 4; ++kq) {
            f32x4 v = *(const f32x4*)(kr + kq * 256 + l * 4);
            ushort4 o;
            o.x = (unsigned short)f2bf(v[0]);
            o.y = (unsigned short)f2bf(v[1]);
            o.z = (unsigned short)f2bf(v[2]);
            o.w = (unsigned short)f2bf(v[3]);
            *(ushort4*)&klds[srow][kq * 256 + l * 4] = o;
        }
    }
    __syncthreads();

    int lrow = l & 15, kgrp = l >> 4;
    f32x4 acc = {0.f, 0.f, 0.f, 0.f};
#pragma unroll
    for (int kk = 0; kk < 8; ++kk) {
        int kj = w * 256 + kk * 32 + kgrp * 8;
        s16x8 af = *(const s16x8*)&klds[lrow][kj];
        s16x8 bf = *(const s16x8*)&ulds[lrow][kj];
        acc = __builtin_amdgcn_mfma_f32_16x16x32_bf16(af, bf, acc, 0, 0, 0);
    }
    redc[w][l] = acc;
    __syncthreads();
    if (t < 64) {
        f32x4 sum = redc[0][t] + redc[1][t] + redc[2][t] + redc[3][t];
        int lr = t & 15, kg = t >> 4;
        size_t obase = ((size_t)b * SL + (s0 + kg * 4)) * NH + lr;
#pragma unroll
        for (int r = 0; r < 4; ++r)
            dot[obase + (size_t)r * NH] = sum[r];
        float m = fmaxf(fmaxf(sum[0], sum[1]), fmaxf(sum[2], sum[3]));
        m = fmaxf(m, __shfl_xor(m, 16));
        m = fmaxf(m, __shfl_xor(m, 32));
        float lsum = __expf(sum[0]-m) + __expf(sum[1]-m) + __expf(sum[2]-m) + __expf(sum[3]-m);
        lsum += __shfl_xor(lsum, 16);
        lsum += __shfl_xor(lsum, 32);
        if (t < 16)
            part[((size_t)b * 128 + st) * 16 + t] = make_float2(m, lsum);
    }
}

// zpart[sq][b][h][j] = sum_{s in tile} dot[b][s][h] * values[s][b][j]
// svpart[sq][b][j]   = sum_{s in tile} values[s][b][j]
// w-reads are 4x ds_read_b128 broadcast (was 16x ds_read_b32: 3.4 TB/s issue ceiling).
__global__ __launch_bounds__(512) void k_zpart(const float* __restrict__ values,
                                               const float* __restrict__ dotb,
                                               float* __restrict__ zpart,
                                               float* __restrict__ svpart) {
    int b  = blockIdx.x & 31;
    int sq = blockIdx.x >> 5;          // 0..7
    int t  = threadIdx.x;
    __shared__ f32x4 wlds4[1024];      // 16 KB: dot[b][sq*256..][16]
    {
        const f32x4* src = (const f32x4*)(dotb + ((size_t)b * SL + sq * 256) * NH);
        wlds4[t]       = src[t];
        wlds4[t + 512] = src[t + 512];
    }
    __syncthreads();

    float ax[NH], ay[NH];
#pragma unroll
    for (int h = 0; h < NH; ++h) { ax[h] = 0.f; ay[h] = 0.f; }
    float svx = 0.f, svy = 0.f;

    const float* vbase = values + ((size_t)(sq * 256) * BSZ + b) * DIM + t * 2;
#pragma unroll 8
    for (int s = 0; s < 256; ++s) {
        float2 v = *(const float2*)(vbase + (size_t)s * (BSZ * DIM));
        const f32x4* wr = wlds4 + s * 4;
        f32x4 w0 = wr[0], w1 = wr[1], w2 = wr[2], w3 = wr[3];
        ax[0]  += v.x * w0[0]; ay[0]  += v.y * w0[0];
        ax[1]  += v.x * w0[1]; ay[1]  += v.y * w0[1];
        ax[2]  += v.x * w0[2]; ay[2]  += v.y * w0[2];
        ax[3]  += v.x * w0[3]; ay[3]  += v.y * w0[3];
        ax[4]  += v.x * w1[0]; ay[4]  += v.y * w1[0];
        ax[5]  += v.x * w1[1]; ay[5]  += v.y * w1[1];
        ax[6]  += v.x * w1[2]; ay[6]  += v.y * w1[2];
        ax[7]  += v.x * w1[3]; ay[7]  += v.y * w1[3];
        ax[8]  += v.x * w2[0]; ay[8]  += v.y * w2[0];
        ax[9]  += v.x * w2[1]; ay[9]  += v.y * w2[1];
        ax[10] += v.x * w2[2]; ay[10] += v.y * w2[2];
        ax[11] += v.x * w2[3]; ay[11] += v.y * w2[3];
        ax[12] += v.x * w3[0]; ay[12] += v.y * w3[0];
        ax[13] += v.x * w3[1]; ay[13] += v.y * w3[1];
        ax[14] += v.x * w3[2]; ay[14] += v.y * w3[2];
        ax[15] += v.x * w3[3]; ay[15] += v.y * w3[3];
        svx += v.x; svy += v.y;
    }
    float* zp = zpart + (size_t)(sq * 32 + b) * NH * DIM + t * 2;
#pragma unroll
    for (int h = 0; h < NH; ++h) {
        float2 o; o.x = ax[h]; o.y = ay[h];
        *(float2*)(zp + (size_t)h * DIM) = o;
    }
    float2 sv; sv.x = svx; sv.y = svy;
    *(float2*)(svpart + (size_t)(sq * 32 + b) * DIM + t * 2) = sv;
}

// attn[b][oc*64+l] = sum_j (sum_p zpart[p][b][oc][j] - T[b][oc]*sum_p svpart[p][b][j]) * Wv[oc*64+l][j]
// grid 128 = 16 oc x 8 bg; block 256 = 4 waves, wave w -> b = bg*4+w. Wv x8 amplification.
__global__ __launch_bounds__(256) void k_attn(const float* __restrict__ zpart,
                                              const float* __restrict__ svpart,
                                              const float2* __restrict__ part,
                                              const float* __restrict__ Wv,
                                              float* __restrict__ attn) {
    int oc = blockIdx.x >> 3;
    int bg = blockIdx.x & 7;
    int t = threadIdx.x, w = t >> 6, l = t & 63;
    int b = bg * 4 + w;
    __shared__ float arow[4][DIM];   // 16 KB

    // T[b][oc] from 128 LSE partials: lane handles 2, then full-wave shfl merge
    float T;
    {
        const float2* pb = part + ((size_t)b * 128) * 16 + oc;
        float2 p0 = pb[(size_t)l * 16];
        float2 p1 = pb[(size_t)(l + 64) * 16];
        float M = fmaxf(p0.x, p1.x);
        float L = p0.y * __expf(p0.x - M) + p1.y * __expf(p1.x - M);
#pragma unroll
        for (int off = 1; off < 64; off <<= 1) {
            float oM = __shfl_xor(M, off);
            float oL = __shfl_xor(L, off);
            float nm = fmaxf(M, oM);
            L = L * __expf(M - nm) + oL * __expf(oM - nm);
            M = nm;
        }
        T = M + __logf(L);
    }
    // stage arow for this wave's b
#pragma unroll
    for (int kq = 0; kq < 4; ++kq) {
        int k = kq * 256 + l * 4;
        f32x4 a = {0,0,0,0}, sv = {0,0,0,0};
#pragma unroll
        for (int p = 0; p < 8; ++p) {
            a  += *(const f32x4*)(zpart + ((size_t)((p * 32 + b) * NH + oc)) * DIM + k);
            sv += *(const f32x4*)(svpart + (size_t)(p * 32 + b) * DIM + k);
        }
        a -= T * sv;
        *(f32x4*)&arow[w][k] = a;
    }
    // GEMM: o = oc*64 + l
    const float* wrow = Wv + (size_t)(oc * 64 + l) * DIM;
    const float* ar = arow[w];
    f32x4 acc = {0,0,0,0};
#pragma unroll 4
    for (int k = 0; k < DIM; k += 4)
        acc += *(const f32x4*)(ar + k) * *(const f32x4*)(wrow + k);
    attn[(size_t)b * DIM + oc * 64 + l] = acc[0] + acc[1] + acc[2] + acc[3];
}

// out[b][oc*64+l] = dot(attn[b][:], Wo[oc*64+l][:]);  same x8-amplification structure.
__global__ __launch_bounds__(256) void k_out(const float* __restrict__ A,
                                             const float* __restrict__ W,
                                             float* __restrict__ O) {
    int oc = blockIdx.x >> 3;
    int bg = blockIdx.x & 7;
    int t = threadIdx.x, w = t >> 6, l = t & 63;
    int b = bg * 4 + w;
    __shared__ float arow[4][DIM];   // 16 KB
#pragma unroll
    for (int kq = 0; kq < 4; ++kq) {
        int k = kq * 256 + l * 4;
        *(f32x4*)&arow[w][k] = *(const f32x4*)(A + (size_t)b * DIM + k);
    }
    const float* wrow = W + (size_t)(oc * 64 + l) * DIM;
    const float* ar = arow[w];
    f32x4 acc = {0,0,0,0};
#pragma unroll 4
    for (int k = 0; k < DIM; k += 4)
        acc += *(const f32x4*)(ar + k) * *(const f32x4*)(wrow + k);
    O[(size_t)b * DIM + oc * 64 + l] = acc[0] + acc[1] + acc[2] + acc[3];
}

extern "C" void kernel_launch(void* const* d_in, const int* in_sizes, int n_in,
                              void* d_out, int out_size, void* d_ws, size_t ws_size,
                              hipStream_t stream) {
    const float* query  = (const float*)d_in[0];
    const float* keys   = (const float*)d_in[1];
    const float* values = (const float*)d_in[2];
    const float* Wq = (const float*)d_in[3];
    const float* Wk = (const float*)d_in[4];
    const float* Wv = (const float*)d_in[5];
    const float* Wo = (const float*)d_in[6];
    float* out = (float*)d_out;

    char* ws = (char*)d_ws;
    short*  u      = (short*)(ws + 0);                        // 1 MB
    float*  dotb   = (float*)(ws + (1 << 20));                // 4 MB  [b][s][h]
    float2* part   = (float2*)(ws + (5 << 20));               // 512 KB [b][128][16]
    float*  zpart  = (float*)(ws + (5 << 20) + (512 << 10));  // 16 MB [8][b][h][j]
    float*  svpart = (float*)(ws + (21 << 20) + (512 << 10)); // 1 MB  [8][b][j]
    float*  attn   = (float*)(ws + (22 << 20) + (512 << 10)); // 128 KB

    hipLaunchKernelGGL(k_qu,    dim3(128),  dim3(256), 0, stream, query, Wq, Wk, u);
    hipLaunchKernelGGL(k_dot2,  dim3(4096), dim3(256), 0, stream, keys, u, dotb, part);
    hipLaunchKernelGGL(k_zpart, dim3(256),  dim3(512), 0, stream, values, dotb, zpart, svpart);
    hipLaunchKernelGGL(k_attn,  dim3(128),  dim3(256), 0, stream, zpart, svpart, part, Wv, attn);
    hipLaunchKernelGGL(k_out,   dim3(128),  dim3(256), 0, stream, attn, Wo, out);
}